// Round 1
// baseline (74.785 us; speedup 1.0000x reference)
//
#include <hip/hip_runtime.h>
#include <math.h>

// Problem constants
#define BS 8
#define T  4096
#define S  4
#define D  257
#define SD (S * D)          // 1028
#define K  (T * D)          // 1,052,672 (t,d) pairs per batch
#define NACC 24             // 4 pp + 4 gg + 16 pg per batch

__global__ __launch_bounds__(256) void zero_ws_kernel(float* ws) {
    int i = blockIdx.x * blockDim.x + threadIdx.x;
    if (i < BS * NACC) ws[i] = 0.0f;
}

// One pass over both tensors. blockIdx.x & 7 selects the batch so every
// block's accumulators belong to exactly one batch.
__global__ __launch_bounds__(256) void partial_kernel(const float* __restrict__ P,
                                                      const float* __restrict__ G,
                                                      float* __restrict__ ws) {
    const int b    = blockIdx.x & 7;
    const int blk  = blockIdx.x >> 3;
    const int nblk = gridDim.x >> 3;             // blocks per batch
    const int stride = nblk * blockDim.x;

    const float* __restrict__ Pb = P + (size_t)b * T * SD;
    const float* __restrict__ Gb = G + (size_t)b * T * SD;

    float pp0 = 0.f, pp1 = 0.f, pp2 = 0.f, pp3 = 0.f;
    float gg0 = 0.f, gg1 = 0.f, gg2 = 0.f, gg3 = 0.f;
    float pg00=0.f, pg01=0.f, pg02=0.f, pg03=0.f;
    float pg10=0.f, pg11=0.f, pg12=0.f, pg13=0.f;
    float pg20=0.f, pg21=0.f, pg22=0.f, pg23=0.f;
    float pg30=0.f, pg31=0.f, pg32=0.f, pg33=0.f;

    for (int i = blk * blockDim.x + threadIdx.x; i < K; i += stride) {
        int t = i / D;                // magic-mul division by 257
        int d = i - t * D;
        const float* p = Pb + (size_t)t * SD + d;
        const float* g = Gb + (size_t)t * SD + d;
        float p0 = p[0], p1 = p[D], p2 = p[2*D], p3 = p[3*D];
        float g0 = g[0], g1 = g[D], g2 = g[2*D], g3 = g[3*D];

        pp0 = fmaf(p0, p0, pp0); pp1 = fmaf(p1, p1, pp1);
        pp2 = fmaf(p2, p2, pp2); pp3 = fmaf(p3, p3, pp3);
        gg0 = fmaf(g0, g0, gg0); gg1 = fmaf(g1, g1, gg1);
        gg2 = fmaf(g2, g2, gg2); gg3 = fmaf(g3, g3, gg3);

        pg00 = fmaf(p0, g0, pg00); pg01 = fmaf(p0, g1, pg01);
        pg02 = fmaf(p0, g2, pg02); pg03 = fmaf(p0, g3, pg03);
        pg10 = fmaf(p1, g0, pg10); pg11 = fmaf(p1, g1, pg11);
        pg12 = fmaf(p1, g2, pg12); pg13 = fmaf(p1, g3, pg13);
        pg20 = fmaf(p2, g0, pg20); pg21 = fmaf(p2, g1, pg21);
        pg22 = fmaf(p2, g2, pg22); pg23 = fmaf(p2, g3, pg23);
        pg30 = fmaf(p3, g0, pg30); pg31 = fmaf(p3, g1, pg31);
        pg32 = fmaf(p3, g2, pg32); pg33 = fmaf(p3, g3, pg33);
    }

    float vals[NACC] = { pp0, pp1, pp2, pp3, gg0, gg1, gg2, gg3,
                         pg00, pg01, pg02, pg03,
                         pg10, pg11, pg12, pg13,
                         pg20, pg21, pg22, pg23,
                         pg30, pg31, pg32, pg33 };

    const int lane = threadIdx.x & 63;
    const int wave = threadIdx.x >> 6;
    __shared__ float sm[4][NACC];

    #pragma unroll
    for (int k = 0; k < NACC; ++k) {
        float v = vals[k];
        #pragma unroll
        for (int o = 32; o > 0; o >>= 1) v += __shfl_down(v, o, 64);
        if (lane == 0) sm[wave][k] = v;
    }
    __syncthreads();
    if (threadIdx.x < NACC) {
        float v = sm[0][threadIdx.x] + sm[1][threadIdx.x]
                + sm[2][threadIdx.x] + sm[3][threadIdx.x];
        atomicAdd(&ws[b * NACC + threadIdx.x], v);
    }
}

// Single-thread finalize: build 4x4 distance matrix per batch, greedy match
// (global argmin, first-in-flat-order tie-break like jnp.argmin), sum, /8.
__global__ void finalize_kernel(const float* __restrict__ ws, float* __restrict__ out) {
    if (threadIdx.x != 0 || blockIdx.x != 0) return;
    float total = 0.f;
    for (int b = 0; b < BS; ++b) {
        const float* w = ws + b * NACC;
        float dist[16];
        for (int s = 0; s < 4; ++s)
            for (int t = 0; t < 4; ++t) {
                float d2 = w[s] + w[4 + t] - 2.f * w[8 + s * 4 + t];
                dist[s * 4 + t] = sqrtf(fmaxf(d2, 0.f));
            }
        bool rdone[4] = {false, false, false, false};
        bool cdone[4] = {false, false, false, false};
        for (int it = 0; it < 4; ++it) {
            float best = INFINITY; int br = 0, bc = 0;
            bool found = false;
            for (int s = 0; s < 4; ++s) {
                if (rdone[s]) continue;
                for (int t = 0; t < 4; ++t) {
                    if (cdone[t]) continue;
                    float v = dist[s * 4 + t];
                    if (!found || v < best) { best = v; br = s; bc = t; found = true; }
                }
            }
            total += best;
            rdone[br] = true; cdone[bc] = true;
        }
    }
    *out = total * 0.125f;
}

extern "C" void kernel_launch(void* const* d_in, const int* in_sizes, int n_in,
                              void* d_out, int out_size, void* d_ws, size_t ws_size,
                              hipStream_t stream) {
    const float* P = (const float*)d_in[0];
    const float* G = (const float*)d_in[1];
    float* out = (float*)d_out;
    float* ws  = (float*)d_ws;   // needs 8*24 floats = 768 B

    zero_ws_kernel<<<1, 256, 0, stream>>>(ws);
    partial_kernel<<<2048, 256, 0, stream>>>(P, G, ws);
    finalize_kernel<<<1, 64, 0, stream>>>(ws, out);
}